// Round 7
// baseline (514.985 us; speedup 1.0000x reference)
//
#include <hip/hip_runtime.h>

// Problem: B=2, T=4096, C=768, H=12, HD=64.
// CERTIFIED INTERFACE (r6): inputs f32 in dict order, sizes
// {6291456,1769472,2304,589824,768}; OUTPUT IS FLOAT32 (reference dtype);
// ws >= 68MB. r3==r4==r5 proved the MFMA pipeline computes the same function
// as pure-f32 VALU; only the output store width was wrong (bf16 vs f32).
// Round 7: round-3 MFMA pipeline + f32 output store.

typedef unsigned short u16;
typedef unsigned int u32;
using bf16x8 = __attribute__((ext_vector_type(8))) short;
using f32x4  = __attribute__((ext_vector_type(4))) float;

__device__ __forceinline__ float bf2f(u16 u) {
  return __uint_as_float(((u32)u) << 16);
}
__device__ __forceinline__ u16 f2bf(float f) {
  u32 u = __float_as_uint(f);
  u += 0x7fffu + ((u >> 16) & 1u);   // RNE
  return (u16)(u >> 16);
}

// ------------------------------------------------------------ canonicalize
__global__ void convert_f32_bf16(const float* __restrict__ src, u16* __restrict__ dst,
                                 int n) {
  const int i0 = blockIdx.x * blockDim.x + threadIdx.x;
  const int stride = gridDim.x * blockDim.x;
  for (int i = i0; i < n; i += stride) dst[i] = f2bf(src[i]);
}

// out[c][r] = (bf16)in[r][c]; R, C multiples of 32. 256 threads.
__global__ void transpose_f32_bf16(const float* __restrict__ in, u16* __restrict__ out,
                                   int R, int C) {
  __shared__ u16 tile[32][33];
  const int c0 = blockIdx.x * 32, r0 = blockIdx.y * 32;
  const int tx = threadIdx.x & 31, ty = threadIdx.x >> 5;
#pragma unroll
  for (int i = 0; i < 32; i += 8)
    tile[ty + i][tx] = f2bf(in[(size_t)(r0 + ty + i) * C + c0 + tx]);
  __syncthreads();
#pragma unroll
  for (int i = 0; i < 32; i += 8)
    out[(size_t)(c0 + ty + i) * R + r0 + tx] = tile[tx][ty + i];
}

// ---------------------------------------------------------------- GEMM (MFMA)
#define LDT 72

__device__ __forceinline__ void stage_tile(u16* lds, const u16* g, int ld, int tid) {
#pragma unroll
  for (int i = 0; i < 4; ++i) {
    const int idx = i * 256 + tid;
    const int r = idx >> 3, c = (idx & 7) * 8;
    *(uint4*)&lds[r * LDT + c] = *(const uint4*)&g[(size_t)r * ld + c];
  }
}

// C = A(M x Kd) * Bt^T (Bt is N x Kd) + bias.  128x128 tile, BK=64, 256 thr.
// MODE 0: scatter bf16 into Q/K/V (B,H,T,64).  MODE 1: f32 row-major (ld 768).
template <int MODE>
__global__ __launch_bounds__(256, 2)
void gemm128(const u16* __restrict__ A, const u16* __restrict__ Bt,
             const u16* __restrict__ bias, void* __restrict__ O0v,
             u16* __restrict__ O1, u16* __restrict__ O2, int Kd) {
  __shared__ __align__(16) u16 As[128 * LDT];
  __shared__ __align__(16) u16 Bs[128 * LDT];
  const int tid = threadIdx.x;
  const int lane = tid & 63, wave = tid >> 6;
  const int wm = wave >> 1, wn = wave & 1;
  const int l16 = lane & 15, quad = lane >> 4;

  const u16* Ag = A + (size_t)blockIdx.x * 128 * Kd;
  const u16* Bg = Bt + (size_t)blockIdx.y * 128 * Kd;

  f32x4 acc[4][4] = {};
  for (int kt = 0; kt < Kd; kt += 64) {
    stage_tile(As, Ag + kt, Kd, tid);
    stage_tile(Bs, Bg + kt, Kd, tid);
    __syncthreads();
#pragma unroll
    for (int s = 0; s < 2; ++s) {
      bf16x8 af[4], bfr[4];
#pragma unroll
      for (int i = 0; i < 4; ++i) {
        const int m = wm * 64 + i * 16 + l16;
        af[i] = *(const bf16x8*)&As[m * LDT + (s * 4 + quad) * 8];
        const int n = wn * 64 + i * 16 + l16;
        bfr[i] = *(const bf16x8*)&Bs[n * LDT + (s * 4 + quad) * 8];
      }
#pragma unroll
      for (int i = 0; i < 4; ++i)
#pragma unroll
        for (int j = 0; j < 4; ++j)
          acc[i][j] = __builtin_amdgcn_mfma_f32_16x16x32_bf16(af[i], bfr[j],
                                                              acc[i][j], 0, 0, 0);
    }
    __syncthreads();
  }

  // C/D layout: col = lane&15, row = quad*4 + r (m89/m91; r3==r5 validated).
#pragma unroll
  for (int i = 0; i < 4; ++i) {
    const int mbase = blockIdx.x * 128 + wm * 64 + i * 16 + quad * 4;
#pragma unroll
    for (int j = 0; j < 4; ++j) {
      const int n = blockIdx.y * 128 + wn * 64 + j * 16 + l16;
      const float bv = bf2f(bias[n]);
#pragma unroll
      for (int r = 0; r < 4; ++r) {
        const int m = mbase + r;
        const float ov = acc[i][j][r] + bv;
        if (MODE == 0) {
          const int b = m >> 12, t = m & 4095;
          const int which = n / 768;
          const int c = n - which * 768;
          const int h = c >> 6, d = c & 63;
          u16* dst = (which == 0) ? (u16*)O0v : ((which == 1) ? O1 : O2);
          dst[((((size_t)b * 12 + h) * 4096 + t) << 6) + d] = f2bf(ov);
        } else {
          ((float*)O0v)[(size_t)m * 768 + n] = ov;   // f32 output!
        }
      }
    }
  }
}

// ---------------------------------------------------------------- attention
// One block per (b, h, 64-row q tile). 4 waves; wave w owns q rows w*16..+15.
// Functionally validated (r3 output == r5 VALU output).
__global__ __launch_bounds__(256, 2)
void attn_kernel(const u16* __restrict__ Q, const u16* __restrict__ K,
                 const u16* __restrict__ V, u16* __restrict__ Y) {
  const int b = blockIdx.z, h = blockIdx.y;
  const int qt = (gridDim.x - 1) - blockIdx.x;  // big tiles first
  const int q0 = qt * 64;
  const size_t headoff = ((size_t)(b * 12 + h)) * 4096 * 64;
  const u16* Qg = Q + headoff + (size_t)q0 * 64;
  const u16* Kg = K + headoff;
  const u16* Vg = V + headoff;

  __shared__ __align__(16) u16 Qs[64 * 72];
  __shared__ __align__(16) u16 Ks[64 * 72];
  __shared__ __align__(16) u16 Vs[64 * 72];       // transposed: [d][kcol]
  __shared__ __align__(16) u16 Ps[4][16 * 72];

  const int tid = threadIdx.x;
  const int lane = tid & 63, wave = tid >> 6;
  const int l16 = lane & 15, quad = lane >> 4;

  for (int c = tid; c < 512; c += 256) {
    const int r = c >> 3, col = (c & 7) * 8;
    *(uint4*)&Qs[r * 72 + col] = *(const uint4*)&Qg[r * 64 + col];
  }
  __syncthreads();
  bf16x8 qf[2];
#pragma unroll
  for (int s = 0; s < 2; ++s)
    qf[s] = *(const bf16x8*)&Qs[(wave * 16 + l16) * 72 + s * 32 + quad * 8];

  float mrow[4], lrow[4];
  f32x4 o[4] = {};
#pragma unroll
  for (int r = 0; r < 4; ++r) { mrow[r] = -1e30f; lrow[r] = 0.f; }

  for (int kt2 = 0; kt2 <= qt; ++kt2) {
    const int t0 = kt2 * 64;
    __syncthreads();
    for (int c = tid; c < 512; c += 256) {
      const int r = c >> 3, col = (c & 7) * 8;
      *(uint4*)&Ks[r * 72 + col] = *(const uint4*)&Kg[(size_t)(t0 + r) * 64 + col];
    }
    for (int c = tid; c < 512; c += 256) {
      const int r = c & 63, d8 = (c >> 6) * 8;
      uint4 pack = *(const uint4*)&Vg[(size_t)(t0 + r) * 64 + d8];
      const u16* e = (const u16*)&pack;
#pragma unroll
      for (int j = 0; j < 8; ++j) Vs[(d8 + j) * 72 + r] = e[j];
    }
    __syncthreads();

    // S = Q K^T
    f32x4 sc[4] = {};
#pragma unroll
    for (int s = 0; s < 2; ++s) {
#pragma unroll
      for (int nt = 0; nt < 4; ++nt) {
        bf16x8 kf = *(const bf16x8*)&Ks[(nt * 16 + l16) * 72 + s * 32 + quad * 8];
        sc[nt] = __builtin_amdgcn_mfma_f32_16x16x32_bf16(qf[s], kf, sc[nt], 0, 0, 0);
      }
    }

    const bool diag = (kt2 == qt);
    float pr[4][4];
    float rmax[4] = {-1e30f, -1e30f, -1e30f, -1e30f};
#pragma unroll
    for (int nt = 0; nt < 4; ++nt)
#pragma unroll
      for (int r = 0; r < 4; ++r) {
        float v = sc[nt][r] * 0.125f;  // 1/sqrt(64)
        if (diag && (t0 + nt * 16 + l16 > q0 + wave * 16 + quad * 4 + r)) v = -1e30f;
        pr[nt][r] = v;
        rmax[r] = fmaxf(rmax[r], v);
      }
#pragma unroll
    for (int r = 0; r < 4; ++r) {
      float t = rmax[r];
      t = fmaxf(t, __shfl_xor(t, 1));
      t = fmaxf(t, __shfl_xor(t, 2));
      t = fmaxf(t, __shfl_xor(t, 4));
      t = fmaxf(t, __shfl_xor(t, 8));
      const float mnew = fmaxf(mrow[r], t);
      const float al = __expf(mrow[r] - mnew);
      mrow[r] = mnew;
      float rs = 0.f;
#pragma unroll
      for (int nt = 0; nt < 4; ++nt) {
        const float p = __expf(pr[nt][r] - mnew);
        pr[nt][r] = p;
        rs += p;
      }
      rs += __shfl_xor(rs, 1);
      rs += __shfl_xor(rs, 2);
      rs += __shfl_xor(rs, 4);
      rs += __shfl_xor(rs, 8);
      lrow[r] = lrow[r] * al + rs;
#pragma unroll
      for (int nt = 0; nt < 4; ++nt) o[nt][r] *= al;
    }

#pragma unroll
    for (int nt = 0; nt < 4; ++nt)
#pragma unroll
      for (int r = 0; r < 4; ++r)
        Ps[wave][(quad * 4 + r) * 72 + nt * 16 + l16] = f2bf(pr[nt][r]);

    __syncthreads();

#pragma unroll
    for (int s2 = 0; s2 < 2; ++s2) {
      bf16x8 pf = *(const bf16x8*)&Ps[wave][l16 * 72 + s2 * 32 + quad * 8];
#pragma unroll
      for (int nt = 0; nt < 4; ++nt) {
        bf16x8 vf = *(const bf16x8*)&Vs[(nt * 16 + l16) * 72 + s2 * 32 + quad * 8];
        o[nt] = __builtin_amdgcn_mfma_f32_16x16x32_bf16(pf, vf, o[nt], 0, 0, 0);
      }
    }
  }

#pragma unroll
  for (int r = 0; r < 4; ++r) {
    const float inv = 1.f / lrow[r];
    const int t = q0 + wave * 16 + quad * 4 + r;
#pragma unroll
    for (int nt = 0; nt < 4; ++nt)
      Y[((size_t)b * 4096 + t) * 768 + h * 64 + nt * 16 + l16] = f2bf(o[nt][r] * inv);
  }
}

// ---------------------------------------------------------------- launch
extern "C" void kernel_launch(void* const* d_in, const int* in_sizes, int n_in,
                              void* d_out, int out_size, void* d_ws, size_t ws_size,
                              hipStream_t stream) {
  (void)in_sizes; (void)n_in; (void)out_size; (void)ws_size;
  const float* x      = (const float*)d_in[0];
  const float* w_attn = (const float*)d_in[1];
  const float* b_attn = (const float*)d_in[2];
  const float* w_proj = (const float*)d_in[3];
  const float* b_proj = (const float*)d_in[4];
  float* out = (float*)d_out;                      // f32 output (certified r6)

  char* ws = (char*)d_ws;
  size_t off = 0;
  auto alloc = [&](size_t bytes) -> void* {
    void* p = ws + off;
    off += (bytes + 255) & ~(size_t)255;
    return p;
  };
  u16* xb  = (u16*)alloc((size_t)8192 * 768 * 2);
  u16* WtA = (u16*)alloc((size_t)2304 * 768 * 2);
  u16* WtP = (u16*)alloc((size_t)768 * 768 * 2);
  u16* ba  = (u16*)alloc(2304 * 2);
  u16* bp  = (u16*)alloc(768 * 2);
  u16* Q   = (u16*)alloc((size_t)6291456 * 2);
  u16* Kp  = (u16*)alloc((size_t)6291456 * 2);
  u16* V   = (u16*)alloc((size_t)6291456 * 2);
  u16* Y   = (u16*)alloc((size_t)6291456 * 2);

  convert_f32_bf16<<<2048, 256, 0, stream>>>(x, xb, 8192 * 768);
  convert_f32_bf16<<<16, 256, 0, stream>>>(b_attn, ba, 2304);
  convert_f32_bf16<<<8, 256, 0, stream>>>(b_proj, bp, 768);
  transpose_f32_bf16<<<dim3(72, 24), 256, 0, stream>>>(w_attn, WtA, 768, 2304);
  transpose_f32_bf16<<<dim3(24, 24), 256, 0, stream>>>(w_proj, WtP, 768, 768);

  gemm128<0><<<dim3(64, 18), 256, 0, stream>>>(xb, WtA, ba, Q, Kp, V, 768);
  attn_kernel<<<dim3(64, 12, 2), 256, 0, stream>>>(Q, Kp, V, Y);
  gemm128<1><<<dim3(64, 6), 256, 0, stream>>>(Y, WtP, bp, out, nullptr, nullptr, 768);
}